// Round 5
// baseline (482.763 us; speedup 1.0000x reference)
//
#include <hip/hip_runtime.h>

#define IMGS 96
#define HW   262144      // 512*512
#define NPTS 12288       // 96*128
#define OOBV 1e-5f

// ws layout (float offsets)
static constexpr size_t PYR_OFF   = 0;        // 8,388,576 floats (levels 1..9, packed)
static constexpr size_t P_OFF     = 8388576;  // 24576
static constexpr size_t SQ_OFF    = 8413152;  // 24576
static constexpr size_t PLMAX_OFF = 8437728;  // 11 floats (plmax[0..10])
static constexpr size_t CNT_OFF   = 8437739;  // 1 int
static constexpr size_t LIST_OFF  = 8437740;  // 12288 ints
static constexpr size_t GA_OFF    = 8450560;  // 25,165,824 floats (ga surface)
// total ~134.5 MB (ws is ~805 MB per poison-fill evidence)

__device__ __forceinline__ int clampi(int v, int lo, int hi) {
    v = v < lo ? lo : v;
    return v > hi ? hi : v;
}

// ---- masks_out scatter + dedup'd owner list + optimizer init + plmax[0] ----
__global__ void k_scatter_init(const float* __restrict__ pts, const float* __restrict__ mt,
                               float* __restrict__ mo, int* __restrict__ cnt,
                               int* __restrict__ plist, float* __restrict__ p,
                               float* __restrict__ sq, float* __restrict__ plmax) {
    int i = blockIdx.x * blockDim.x + threadIdx.x;
    if (i >= NPTS) return;
    float px = pts[2*i], py = pts[2*i+1];
    int xi = clampi((int)rintf(px), 0, 511);
    int yi = clampi((int)rintf(py), 0, 511);
    int img = i >> 7, n = i & 127;
    int gp = img * HW + yi * 512 + xi;
    float old = atomicExch(&mo[gp], 1.0f);
    if (old == 0.0f) {                 // first claimer owns this pixel
        int k = atomicAdd(cnt, 1);
        plist[k] = gp;
    }
    p[2*i] = px; p[2*i+1] = py;
    sq[2*i] = 0.0f; sq[2*i+1] = 0.0f;
    float d = expf(-(float)n * 0.078125f);      // exp(-n/128*10), exact args
    float pl = (1.0f - mt[(size_t)img * HW + yi*512 + xi]) * d;
    atomicMax((int*)plmax, __float_as_int(pl)); // pl>0 => int-bit order == float order
}

// ---- level 1 (256^2) from -masks_target only (0.01*mo added as correction) ----
__global__ void k_lvl1(const float* __restrict__ mt, float* __restrict__ out) {
    int t = blockIdx.x * blockDim.x + threadIdx.x;
    if (t >= IMGS * 65536) return;
    int j = t & 255, i = (t >> 8) & 255, img = t >> 16;
    const float* m = mt + (size_t)img * HW;
    float s = 0.0f;
    #pragma unroll
    for (int dy = -1; dy <= 1; ++dy) {
        int y = 2*i + dy;
        #pragma unroll
        for (int dx = -1; dx <= 1; ++dx) {
            int x = 2*j + dx;
            s += (y >= 0 && y < 512 && x >= 0 && x < 512) ? -m[y*512 + x] : OOBV;
        }
    }
    out[t] = s / 9.0f;
}

// ---- sparse correction: each set pixel adds 0.01/9 to covering lvl1 cells ----
__global__ void k_corr1(const int* __restrict__ cnt, const int* __restrict__ plist,
                        float* __restrict__ lvl1) {
    int k = blockIdx.x * blockDim.x + threadIdx.x;
    if (k >= *cnt) return;
    int gp = plist[k];
    int img = gp >> 18;
    int r = gp & (HW - 1);
    int y = r >> 9, x = r & 511;
    float* L = lvl1 + (size_t)img * 65536;
    const float c = 0.01f / 9.0f;
    int ilo = y >> 1, ihi = ((y + 1) >> 1) > 255 ? 255 : ((y + 1) >> 1);
    int jlo = x >> 1, jhi = ((x + 1) >> 1) > 255 ? 255 : ((x + 1) >> 1);
    for (int i = ilo; i <= ihi; ++i)
        for (int j = jlo; j <= jhi; ++j)
            atomicAdd(&L[i*256 + j], c);
}

// ---- level 2 (128^2) from level 1 (256^2) ----
__global__ void k_lvl2(const float* __restrict__ in, float* __restrict__ out) {
    int t = blockIdx.x * blockDim.x + threadIdx.x;
    if (t >= IMGS * 16384) return;
    int j = t & 127, i = (t >> 7) & 127, img = t >> 14;
    const float* m = in + (size_t)img * 65536;
    float s = 0.0f;
    #pragma unroll
    for (int dy = -1; dy <= 1; ++dy) {
        int y = 2*i + dy;
        #pragma unroll
        for (int dx = -1; dx <= 1; ++dx) {
            int x = 2*j + dx;
            s += (y >= 0 && y < 256 && x >= 0 && x < 256) ? m[y*256 + x] : OOBV;
        }
    }
    out[t] = s / 9.0f;
}

// ---- levels 3..9 fused, one block per image, LDS resident ----
__global__ __launch_bounds__(256) void k_pyrtail(float* __restrict__ pyr) {
    __shared__ float buf[5461];   // 64^2 + 32^2 + 16^2 + 8^2 + 4^2 + 2^2 + 1
    int img = blockIdx.x;
    const float* L2 = pyr + 6291456 + (size_t)img * 16384;   // lvl2
    // level 3 (64^2) from global lvl2 (128^2)
    for (int t = threadIdx.x; t < 4096; t += 256) {
        int i = t >> 6, j = t & 63;
        float s = 0.0f;
        #pragma unroll
        for (int dy = -1; dy <= 1; ++dy) {
            int y = 2*i + dy;
            #pragma unroll
            for (int dx = -1; dx <= 1; ++dx) {
                int x = 2*j + dx;
                s += (y >= 0 && y < 128 && x >= 0 && x < 128) ? L2[y*128 + x] : OOBV;
            }
        }
        float v = s / 9.0f;
        buf[t] = v;
        pyr[7864320 + (size_t)img * 4096 + t] = v;
    }
    __syncthreads();
    // levels 4..9 from LDS
    int inOff = 0, sin = 64;
    size_t goff = 8257536;
    while (sin > 1) {
        int sout = sin >> 1;
        int outOff = inOff + sin * sin;
        for (int t = threadIdx.x; t < sout * sout; t += 256) {
            int i = t / sout, j = t - i * sout;
            float s = 0.0f;
            for (int dy = -1; dy <= 1; ++dy) {
                int y = 2*i + dy;
                for (int dx = -1; dx <= 1; ++dx) {
                    int x = 2*j + dx;
                    s += (y >= 0 && y < sin && x >= 0 && x < sin) ? buf[inOff + y*sin + x] : OOBV;
                }
            }
            float v = s / 9.0f;
            buf[outOff + t] = v;
            pyr[goff + (size_t)img * sout * sout + t] = v;
        }
        __syncthreads();
        inOff = outOff; sin = sout;
        goff += (size_t)96 * sout * sout;
    }
}

// ---- ga = (grad0 + sum of upsampled levels)/10, one block per image-row ----
__global__ __launch_bounds__(256) void k_ga(const float* __restrict__ mt,
                                            const float* __restrict__ pyr,
                                            float* __restrict__ ga) {
    __shared__ float vrow[520];
    int img = blockIdx.x >> 9;
    int h = blockIdx.x & 511;
    float hf = (float)h;

    // phase 1: vertically interpolated rows of levels 1..9 (+dup pad slot each)
    for (int e = threadIdx.x; e < 520; e += 256) {
        int l = 0, rem = e;
        while (true) {
            int len = (256 >> l) + 1;
            if (rem < len) break;
            rem -= len; ++l;
        }
        int s = 256 >> l;
        int x = rem < s ? rem : s - 1;          // pad slot duplicates last col
        float scale = (float)s * (1.0f / 512.0f);
        float fy = (hf + 0.5f) * scale - 0.5f;
        fy = fminf(fmaxf(fy, 0.0f), (float)(s - 1));   // edge clamp => exact weight-1
        float fyf = floorf(fy);
        int y0 = (int)fyf;
        float ty = fy - fyf;
        int yb = (y0 + 1 < s) ? y0 + 1 : s - 1;
        const float* Lp = pyr + (8388608 - (8388608 >> (2*l))) + (size_t)img * s * s;
        float a = Lp[y0*s + x], b = Lp[yb*s + x];
        vrow[e] = (1.0f - ty) * a + ty * b;
    }
    __syncthreads();

    // phase 2: two pixels per thread
    #pragma unroll
    for (int rep = 0; rep < 2; ++rep) {
        int w = threadIdx.x + rep * 256;
        int idx = img * HW + h * 512 + w;
        float wf = (float)w;
        float acc = -mt[idx];                   // grad0 (0.01*mo corrected later)
        #pragma unroll
        for (int l = 0; l < 9; ++l) {
            const int s = 256 >> l;
            const float scale = (float)s * (1.0f / 512.0f);
            float fx = (wf + 0.5f) * scale - 0.5f;
            fx = fminf(fmaxf(fx, 0.0f), (float)(s - 1));
            float fxf = floorf(fx);
            int x0 = (int)fxf;
            float tx = fx - fxf;
            const int vo = 512 - (512 >> l) + l;
            float a = vrow[vo + x0], b = vrow[vo + x0 + 1];
            acc += (1.0f - tx) * a + tx * b;
        }
        ga[idx] = acc / 10.0f;
    }
}

// ---- ga correction: +0.01/10 at set pixels (dedup'd, so plain RMW is safe) ----
__global__ void k_corrga(const int* __restrict__ cnt, const int* __restrict__ plist,
                         float* __restrict__ ga) {
    int k = blockIdx.x * blockDim.x + threadIdx.x;
    if (k >= *cnt) return;
    ga[plist[k]] += 0.001f;
}

// ---- one RMSprop step; carries plmax[t] -> plmax[t+1] ----
__global__ void k_step(const float* __restrict__ mt, const float* __restrict__ ga,
                       float* __restrict__ p, float* __restrict__ sq,
                       float* __restrict__ plmax, int t) {
    int i = blockIdx.x * blockDim.x + threadIdx.x;
    if (i >= NPTS) return;
    float plm = plmax[t];
    if (!(plm > 0.1f)) {                        // inactive: p frozen, propagate max
        if (i == 0) plmax[t+1] = plm;
        return;
    }
    float px = p[2*i], py = p[2*i+1];
    int xi = clampi((int)rintf(px), 0, 511);
    int yi = clampi((int)rintf(py), 0, 511);
    int img = i >> 7, n = i & 127;
    const float* M = mt + (size_t)img * HW;
    const float* G = ga + (size_t)img * HW;
    float d = expf(-(float)n * 0.078125f);
    float pl = (1.0f - M[yi*512 + xi]) * d;
    float gxp = (G[clampi(yi-1,0,511)*512 + xi] - G[clampi(yi+1,0,511)*512 + xi]) * 0.5f;
    float gyp = (G[yi*512 + clampi(xi-1,0,511)] - G[yi*512 + clampi(xi+1,0,511)]) * 0.5f;
    float g0 = -gyp * pl;                       // x component
    float g1 = -gxp * pl;                       // y component
    float s0 = 0.99f * sq[2*i]   + 0.01f * g0 * g0;
    float s1 = 0.99f * sq[2*i+1] + 0.01f * g1 * g1;
    float p0 = px - 0.2f * g0 / (sqrtf(s0) + 1e-8f);
    float p1 = py - 0.2f * g1 / (sqrtf(s1) + 1e-8f);
    p[2*i] = p0; p[2*i+1] = p1;
    sq[2*i] = s0; sq[2*i+1] = s1;
    int xi2 = clampi((int)rintf(p0), 0, 511);
    int yi2 = clampi((int)rintf(p1), 0, 511);
    float pl2 = (1.0f - M[yi2*512 + xi2]) * d;
    atomicMax((int*)(plmax + t + 1), __float_as_int(pl2));
}

// ---- final: masks_opt scatter + p_opt write ----
__global__ void k_final(const float* __restrict__ p, float* __restrict__ mopt,
                        float* __restrict__ pout) {
    int i = blockIdx.x * blockDim.x + threadIdx.x;
    if (i >= NPTS) return;
    float px = p[2*i], py = p[2*i+1];
    pout[2*i] = px; pout[2*i+1] = py;
    int xi = clampi((int)rintf(px), 0, 511);
    int yi = clampi((int)rintf(py), 0, 511);
    mopt[(i >> 7) * HW + yi*512 + xi] = 1.0f;
}

extern "C" void kernel_launch(void* const* d_in, const int* in_sizes, int n_in,
                              void* d_out, int out_size, void* d_ws, size_t ws_size,
                              hipStream_t stream) {
    const float* pts = (const float*)d_in[0];
    const float* mt  = (const float*)d_in[1];
    if (in_sizes[0] != NPTS * 2) { const float* tmp = pts; pts = mt; mt = tmp; }

    float* out  = (float*)d_out;
    float* mo   = out;                          // masks_out
    float* mopt = out + (size_t)IMGS * HW;      // masks_opt
    float* pout = out + 2 * (size_t)IMGS * HW;  // p_opt

    float* ws    = (float*)d_ws;
    float* pyr   = ws + PYR_OFF;
    float* p     = ws + P_OFF;
    float* sq    = ws + SQ_OFF;
    float* plmax = ws + PLMAX_OFF;
    int*   cnt   = (int*)(ws + CNT_OFF);
    int*   plist = (int*)(ws + LIST_OFF);
    float* ga    = ws + GA_OFF;

    // zero entire output (masks_out + masks_opt zeros; p_opt overwritten later)
    hipMemsetAsync(out, 0, (size_t)out_size * sizeof(float), stream);
    hipMemsetAsync(plmax, 0, 12 * sizeof(float), stream);   // plmax[0..10] + cnt

    k_scatter_init<<<NPTS/256, 256, 0, stream>>>(pts, mt, mo, cnt, plist, p, sq, plmax);
    k_lvl1<<<IMGS*65536/256, 256, 0, stream>>>(mt, pyr);
    k_corr1<<<NPTS/256, 256, 0, stream>>>(cnt, plist, pyr);
    k_lvl2<<<IMGS*16384/256, 256, 0, stream>>>(pyr, pyr + 6291456);
    k_pyrtail<<<IMGS, 256, 0, stream>>>(pyr);
    k_ga<<<IMGS*512, 256, 0, stream>>>(mt, pyr, ga);
    k_corrga<<<NPTS/256, 256, 0, stream>>>(cnt, plist, ga);
    for (int t = 0; t < 10; ++t)
        k_step<<<NPTS/256, 256, 0, stream>>>(mt, ga, p, sq, plmax, t);
    k_final<<<NPTS/256, 256, 0, stream>>>(p, mopt, pout);
}

// Round 6
// 433.471 us; speedup vs baseline: 1.1137x; 1.1137x over previous
//
#include <hip/hip_runtime.h>

#define IMGS 96
#define HW   262144      // 512*512
#define NPTS 12288       // 96*128
#define OOBV 1e-5f

// ws layout (float offsets)
static constexpr size_t PYR_OFF   = 0;        // 8,388,576 floats (levels 1..9, packed)
static constexpr size_t PFIN_OFF  = 8388576;  // 24576 floats (final p)
static constexpr size_t PLMAX_OFF = 8413152;  // 11 floats (plmax[0..10])
static constexpr size_t CNT_OFF   = 8413163;  // 1 int
static constexpr size_t LIST_OFF  = 8413164;  // 12288 ints
static constexpr size_t GA_OFF    = 8425472;  // 25,165,824 floats (ga surface)
// total ~134.4 MB (ws is ~805 MB per poison-fill evidence)

__device__ __forceinline__ int clampi(int v, int lo, int hi) {
    v = v < lo ? lo : v;
    return v > hi ? hi : v;
}

// ---- masks_out scatter + dedup'd owner list of set pixels ----
__global__ void k_scatter(const float* __restrict__ pts, float* __restrict__ mo,
                          int* __restrict__ cnt, int* __restrict__ plist) {
    int i = blockIdx.x * blockDim.x + threadIdx.x;
    if (i >= NPTS) return;
    float px = pts[2*i], py = pts[2*i+1];
    int xi = clampi((int)rintf(px), 0, 511);
    int yi = clampi((int)rintf(py), 0, 511);
    int gp = (i >> 7) * HW + yi * 512 + xi;
    float old = atomicExch(&mo[gp], 1.0f);
    if (old == 0.0f) {                 // first claimer owns this pixel
        int k = atomicAdd(cnt, 1);
        plist[k] = gp;
    }
}

// ---- level 1 (256^2) from -masks_target only (0.01*mo added as correction) ----
__global__ void k_lvl1(const float* __restrict__ mt, float* __restrict__ out) {
    int t = blockIdx.x * blockDim.x + threadIdx.x;
    if (t >= IMGS * 65536) return;
    int j = t & 255, i = (t >> 8) & 255, img = t >> 16;
    const float* m = mt + (size_t)img * HW;
    float s = 0.0f;
    #pragma unroll
    for (int dy = -1; dy <= 1; ++dy) {
        int y = 2*i + dy;
        #pragma unroll
        for (int dx = -1; dx <= 1; ++dx) {
            int x = 2*j + dx;
            s += (y >= 0 && y < 512 && x >= 0 && x < 512) ? -m[y*512 + x] : OOBV;
        }
    }
    out[t] = s / 9.0f;
}

// ---- sparse correction: each set pixel adds 0.01/9 to covering lvl1 cells ----
__global__ void k_corr1(const int* __restrict__ cnt, const int* __restrict__ plist,
                        float* __restrict__ lvl1) {
    int k = blockIdx.x * blockDim.x + threadIdx.x;
    if (k >= *cnt) return;
    int gp = plist[k];
    int img = gp >> 18;
    int r = gp & (HW - 1);
    int y = r >> 9, x = r & 511;
    float* L = lvl1 + (size_t)img * 65536;
    const float c = 0.01f / 9.0f;
    int ilo = y >> 1, ihi = ((y + 1) >> 1) > 255 ? 255 : ((y + 1) >> 1);
    int jlo = x >> 1, jhi = ((x + 1) >> 1) > 255 ? 255 : ((x + 1) >> 1);
    for (int i = ilo; i <= ihi; ++i)
        for (int j = jlo; j <= jhi; ++j)
            atomicAdd(&L[i*256 + j], c);
}

// ---- level 2 (128^2) from level 1 (256^2) ----
__global__ void k_lvl2(const float* __restrict__ in, float* __restrict__ out) {
    int t = blockIdx.x * blockDim.x + threadIdx.x;
    if (t >= IMGS * 16384) return;
    int j = t & 127, i = (t >> 7) & 127, img = t >> 14;
    const float* m = in + (size_t)img * 65536;
    float s = 0.0f;
    #pragma unroll
    for (int dy = -1; dy <= 1; ++dy) {
        int y = 2*i + dy;
        #pragma unroll
        for (int dx = -1; dx <= 1; ++dx) {
            int x = 2*j + dx;
            s += (y >= 0 && y < 256 && x >= 0 && x < 256) ? m[y*256 + x] : OOBV;
        }
    }
    out[t] = s / 9.0f;
}

// ---- levels 3..9 fused, one block per image, LDS resident ----
__global__ __launch_bounds__(256) void k_pyrtail(float* __restrict__ pyr) {
    __shared__ float buf[5461];   // 64^2 + 32^2 + 16^2 + 8^2 + 4^2 + 2^2 + 1
    int img = blockIdx.x;
    const float* L2 = pyr + 6291456 + (size_t)img * 16384;   // lvl2
    // level 3 (64^2) from global lvl2 (128^2)
    for (int t = threadIdx.x; t < 4096; t += 256) {
        int i = t >> 6, j = t & 63;
        float s = 0.0f;
        #pragma unroll
        for (int dy = -1; dy <= 1; ++dy) {
            int y = 2*i + dy;
            #pragma unroll
            for (int dx = -1; dx <= 1; ++dx) {
                int x = 2*j + dx;
                s += (y >= 0 && y < 128 && x >= 0 && x < 128) ? L2[y*128 + x] : OOBV;
            }
        }
        float v = s / 9.0f;
        buf[t] = v;
        pyr[7864320 + (size_t)img * 4096 + t] = v;
    }
    __syncthreads();
    // levels 4..9 from LDS
    int inOff = 0, sin = 64;
    size_t goff = 8257536;
    while (sin > 1) {
        int sout = sin >> 1;
        int outOff = inOff + sin * sin;
        for (int t = threadIdx.x; t < sout * sout; t += 256) {
            int i = t / sout, j = t - i * sout;
            float s = 0.0f;
            for (int dy = -1; dy <= 1; ++dy) {
                int y = 2*i + dy;
                for (int dx = -1; dx <= 1; ++dx) {
                    int x = 2*j + dx;
                    s += (y >= 0 && y < sin && x >= 0 && x < sin) ? buf[inOff + y*sin + x] : OOBV;
                }
            }
            float v = s / 9.0f;
            buf[outOff + t] = v;
            pyr[goff + (size_t)img * sout * sout + t] = v;
        }
        __syncthreads();
        inOff = outOff; sin = sout;
        goff += (size_t)96 * sout * sout;
    }
}

// ---- ga = (grad0 + sum of upsampled levels)/10, one block per image-row ----
__global__ __launch_bounds__(256) void k_ga(const float* __restrict__ mt,
                                            const float* __restrict__ pyr,
                                            float* __restrict__ ga) {
    __shared__ float vrow[520];
    int img = blockIdx.x >> 9;
    int h = blockIdx.x & 511;
    float hf = (float)h;

    // phase 1: vertically interpolated rows of levels 1..9 (+dup pad slot each)
    for (int e = threadIdx.x; e < 520; e += 256) {
        int l = 0, rem = e;
        while (true) {
            int len = (256 >> l) + 1;
            if (rem < len) break;
            rem -= len; ++l;
        }
        int s = 256 >> l;
        int x = rem < s ? rem : s - 1;          // pad slot duplicates last col
        float scale = (float)s * (1.0f / 512.0f);
        float fy = (hf + 0.5f) * scale - 0.5f;
        fy = fminf(fmaxf(fy, 0.0f), (float)(s - 1));   // edge clamp => exact weight-1
        float fyf = floorf(fy);
        int y0 = (int)fyf;
        float ty = fy - fyf;
        int yb = (y0 + 1 < s) ? y0 + 1 : s - 1;
        const float* Lp = pyr + (8388608 - (8388608 >> (2*l))) + (size_t)img * s * s;
        float a = Lp[y0*s + x], b = Lp[yb*s + x];
        vrow[e] = (1.0f - ty) * a + ty * b;
    }
    __syncthreads();

    // phase 2: two pixels per thread
    #pragma unroll
    for (int rep = 0; rep < 2; ++rep) {
        int w = threadIdx.x + rep * 256;
        int idx = img * HW + h * 512 + w;
        float wf = (float)w;
        float acc = -mt[idx];                   // grad0 (0.01*mo corrected later)
        #pragma unroll
        for (int l = 0; l < 9; ++l) {
            const int s = 256 >> l;
            const float scale = (float)s * (1.0f / 512.0f);
            float fx = (wf + 0.5f) * scale - 0.5f;
            fx = fminf(fmaxf(fx, 0.0f), (float)(s - 1));
            float fxf = floorf(fx);
            int x0 = (int)fxf;
            float tx = fx - fxf;
            const int vo = 512 - (512 >> l) + l;
            float a = vrow[vo + x0], b = vrow[vo + x0 + 1];
            acc += (1.0f - tx) * a + tx * b;
        }
        ga[idx] = acc / 10.0f;
    }
}

// ---- ga correction: +0.01/10 at set pixels (dedup'd, so plain RMW is safe) ----
__global__ void k_corrga(const int* __restrict__ cnt, const int* __restrict__ plist,
                         float* __restrict__ ga) {
    int k = blockIdx.x * blockDim.x + threadIdx.x;
    if (k >= *cnt) return;
    ga[plist[k]] += 0.001f;
}

// ---- speculative full trajectory: 10 steps, no grid sync ----
// Valid because the gate has latch semantics: trajectories agree with the
// reference up to the first t where plmax[t] <= 0.1; k_fix truncates if needed.
__global__ __launch_bounds__(256) void k_traj(const float* __restrict__ pts,
                                              const float* __restrict__ mt,
                                              const float* __restrict__ ga,
                                              float* __restrict__ pfin,
                                              float* __restrict__ plmax) {
    int i = blockIdx.x * 256 + threadIdx.x;    // grid exactly 48x256 = NPTS
    float px = pts[2*i], py = pts[2*i+1];
    int img = i >> 7, n = i & 127;
    const float* M = mt + (size_t)img * HW;
    const float* G = ga + (size_t)img * HW;
    float d = expf(-(float)n * 0.078125f);     // exp(-n/128*10)
    float s0 = 0.0f, s1 = 0.0f;

    for (int t = 0; t < 10; ++t) {
        int xi = clampi((int)rintf(px), 0, 511);
        int yi = clampi((int)rintf(py), 0, 511);
        float pl = (1.0f - M[yi*512 + xi]) * d;
        // wave-level max reduce, one atomic per wave per step
        float r = pl;
        #pragma unroll
        for (int off = 32; off; off >>= 1) r = fmaxf(r, __shfl_xor(r, off, 64));
        if ((threadIdx.x & 63) == 0)
            atomicMax((int*)&plmax[t], __float_as_int(r));  // pl>=0 => bit order ok
        float gxp = (G[clampi(yi-1,0,511)*512 + xi] - G[clampi(yi+1,0,511)*512 + xi]) * 0.5f;
        float gyp = (G[yi*512 + clampi(xi-1,0,511)] - G[yi*512 + clampi(xi+1,0,511)]) * 0.5f;
        float g0 = -gyp * pl;                  // x component
        float g1 = -gxp * pl;                  // y component
        s0 = 0.99f * s0 + 0.01f * g0 * g0;
        s1 = 0.99f * s1 + 0.01f * g1 * g1;
        px = px - 0.2f * g0 / (sqrtf(s0) + 1e-8f);
        py = py - 0.2f * g1 / (sqrtf(s1) + 1e-8f);
    }
    pfin[2*i] = px; pfin[2*i+1] = py;
}

// ---- truncation fixup: replay tstop steps if any gate failed (rare) ----
__global__ __launch_bounds__(256) void k_fix(const float* __restrict__ pts,
                                             const float* __restrict__ mt,
                                             const float* __restrict__ ga,
                                             float* __restrict__ pfin,
                                             const float* __restrict__ plmax) {
    int tstop = 10;
    for (int t = 0; t < 10; ++t) {
        if (!(plmax[t] > 0.1f)) { tstop = t; break; }
    }
    if (tstop == 10) return;                   // speculation was exact (normal path)
    int i = blockIdx.x * 256 + threadIdx.x;
    float px = pts[2*i], py = pts[2*i+1];
    int img = i >> 7, n = i & 127;
    const float* M = mt + (size_t)img * HW;
    const float* G = ga + (size_t)img * HW;
    float d = expf(-(float)n * 0.078125f);
    float s0 = 0.0f, s1 = 0.0f;
    for (int t = 0; t < tstop; ++t) {
        int xi = clampi((int)rintf(px), 0, 511);
        int yi = clampi((int)rintf(py), 0, 511);
        float pl = (1.0f - M[yi*512 + xi]) * d;
        float gxp = (G[clampi(yi-1,0,511)*512 + xi] - G[clampi(yi+1,0,511)*512 + xi]) * 0.5f;
        float gyp = (G[yi*512 + clampi(xi-1,0,511)] - G[yi*512 + clampi(xi+1,0,511)]) * 0.5f;
        float g0 = -gyp * pl;
        float g1 = -gxp * pl;
        s0 = 0.99f * s0 + 0.01f * g0 * g0;
        s1 = 0.99f * s1 + 0.01f * g1 * g1;
        px = px - 0.2f * g0 / (sqrtf(s0) + 1e-8f);
        py = py - 0.2f * g1 / (sqrtf(s1) + 1e-8f);
    }
    pfin[2*i] = px; pfin[2*i+1] = py;
}

// ---- final: masks_opt scatter + p_opt write ----
__global__ void k_final(const float* __restrict__ p, float* __restrict__ mopt,
                        float* __restrict__ pout) {
    int i = blockIdx.x * blockDim.x + threadIdx.x;
    if (i >= NPTS) return;
    float px = p[2*i], py = p[2*i+1];
    pout[2*i] = px; pout[2*i+1] = py;
    int xi = clampi((int)rintf(px), 0, 511);
    int yi = clampi((int)rintf(py), 0, 511);
    mopt[(i >> 7) * HW + yi*512 + xi] = 1.0f;
}

extern "C" void kernel_launch(void* const* d_in, const int* in_sizes, int n_in,
                              void* d_out, int out_size, void* d_ws, size_t ws_size,
                              hipStream_t stream) {
    const float* pts = (const float*)d_in[0];
    const float* mt  = (const float*)d_in[1];
    if (in_sizes[0] != NPTS * 2) { const float* tmp = pts; pts = mt; mt = tmp; }

    float* out  = (float*)d_out;
    float* mo   = out;                          // masks_out
    float* mopt = out + (size_t)IMGS * HW;      // masks_opt
    float* pout = out + 2 * (size_t)IMGS * HW;  // p_opt

    float* ws    = (float*)d_ws;
    float* pyr   = ws + PYR_OFF;
    float* pfin  = ws + PFIN_OFF;
    float* plmax = ws + PLMAX_OFF;
    int*   cnt   = (int*)(ws + CNT_OFF);
    int*   plist = (int*)(ws + LIST_OFF);
    float* ga    = ws + GA_OFF;

    // zero entire output (masks_out + masks_opt zeros; p_opt overwritten later)
    hipMemsetAsync(out, 0, (size_t)out_size * sizeof(float), stream);
    hipMemsetAsync(plmax, 0, 12 * sizeof(float), stream);   // plmax[0..10] + cnt

    k_scatter<<<NPTS/256, 256, 0, stream>>>(pts, mo, cnt, plist);
    k_lvl1<<<IMGS*65536/256, 256, 0, stream>>>(mt, pyr);
    k_corr1<<<NPTS/256, 256, 0, stream>>>(cnt, plist, pyr);
    k_lvl2<<<IMGS*16384/256, 256, 0, stream>>>(pyr, pyr + 6291456);
    k_pyrtail<<<IMGS, 256, 0, stream>>>(pyr);
    k_ga<<<IMGS*512, 256, 0, stream>>>(mt, pyr, ga);
    k_corrga<<<NPTS/256, 256, 0, stream>>>(cnt, plist, ga);
    k_traj<<<NPTS/256, 256, 0, stream>>>(pts, mt, ga, pfin, plmax);
    k_fix<<<NPTS/256, 256, 0, stream>>>(pts, mt, ga, pfin, plmax);
    k_final<<<NPTS/256, 256, 0, stream>>>(pfin, mopt, pout);
}

// Round 7
// 426.917 us; speedup vs baseline: 1.1308x; 1.0154x over previous
//
#include <hip/hip_runtime.h>

#define IMGS 96
#define HW   262144      // 512*512
#define NPTS 12288       // 96*128
#define OOBV 1e-5f

// ws layout (float offsets)
static constexpr size_t PYR_OFF   = 0;        // 8,388,576 floats (levels 1..9, packed)
static constexpr size_t PFIN_OFF  = 8388576;  // 24576 floats (final p)
static constexpr size_t PLMAX_OFF = 8413152;  // 11 floats (plmax[0..10])
static constexpr size_t CNT_OFF   = 8413163;  // 1 int
static constexpr size_t LIST_OFF  = 8413164;  // 12288 ints
static constexpr size_t GA_OFF    = 8425472;  // 25,165,824 floats (ga surface)

__device__ __forceinline__ int clampi(int v, int lo, int hi) {
    v = v < lo ? lo : v;
    return v > hi ? hi : v;
}

// ---- masks_out scatter + dedup'd owner list of set pixels ----
__global__ void k_scatter(const float* __restrict__ pts, float* __restrict__ mo,
                          int* __restrict__ cnt, int* __restrict__ plist) {
    int i = blockIdx.x * blockDim.x + threadIdx.x;
    if (i >= NPTS) return;
    float px = pts[2*i], py = pts[2*i+1];
    int xi = clampi((int)rintf(px), 0, 511);
    int yi = clampi((int)rintf(py), 0, 511);
    int gp = (i >> 7) * HW + yi * 512 + xi;
    float old = atomicExch(&mo[gp], 1.0f);
    if (old == 0.0f) {                 // first claimer owns this pixel
        int k = atomicAdd(cnt, 1);
        plist[k] = gp;
    }
}

// ---- level 1 (256^2) from -masks_target only (0.01*mo added as correction) ----
__global__ void k_lvl1(const float* __restrict__ mt, float* __restrict__ out) {
    int t = blockIdx.x * blockDim.x + threadIdx.x;
    if (t >= IMGS * 65536) return;
    int j = t & 255, i = (t >> 8) & 255, img = t >> 16;
    const float* m = mt + (size_t)img * HW;
    float s = 0.0f;
    #pragma unroll
    for (int dy = -1; dy <= 1; ++dy) {
        int y = 2*i + dy;
        #pragma unroll
        for (int dx = -1; dx <= 1; ++dx) {
            int x = 2*j + dx;
            s += (y >= 0 && y < 512 && x >= 0 && x < 512) ? -m[y*512 + x] : OOBV;
        }
    }
    out[t] = s / 9.0f;
}

// ---- sparse correction: each set pixel adds 0.01/9 to covering lvl1 cells ----
__global__ void k_corr1(const int* __restrict__ cnt, const int* __restrict__ plist,
                        float* __restrict__ lvl1) {
    int k = blockIdx.x * blockDim.x + threadIdx.x;
    if (k >= *cnt) return;
    int gp = plist[k];
    int img = gp >> 18;
    int r = gp & (HW - 1);
    int y = r >> 9, x = r & 511;
    float* L = lvl1 + (size_t)img * 65536;
    const float c = 0.01f / 9.0f;
    int ilo = y >> 1, ihi = ((y + 1) >> 1) > 255 ? 255 : ((y + 1) >> 1);
    int jlo = x >> 1, jhi = ((x + 1) >> 1) > 255 ? 255 : ((x + 1) >> 1);
    for (int i = ilo; i <= ihi; ++i)
        for (int j = jlo; j <= jhi; ++j)
            atomicAdd(&L[i*256 + j], c);
}

// ---- level 2 (128^2) from level 1 (256^2) ----
__global__ void k_lvl2(const float* __restrict__ in, float* __restrict__ out) {
    int t = blockIdx.x * blockDim.x + threadIdx.x;
    if (t >= IMGS * 16384) return;
    int j = t & 127, i = (t >> 7) & 127, img = t >> 14;
    const float* m = in + (size_t)img * 65536;
    float s = 0.0f;
    #pragma unroll
    for (int dy = -1; dy <= 1; ++dy) {
        int y = 2*i + dy;
        #pragma unroll
        for (int dx = -1; dx <= 1; ++dx) {
            int x = 2*j + dx;
            s += (y >= 0 && y < 256 && x >= 0 && x < 256) ? m[y*256 + x] : OOBV;
        }
    }
    out[t] = s / 9.0f;
}

// ---- levels 3..9 fused, one block per image, LDS resident ----
__global__ __launch_bounds__(256) void k_pyrtail(float* __restrict__ pyr) {
    __shared__ float buf[5461];   // 64^2 + 32^2 + 16^2 + 8^2 + 4^2 + 2^2 + 1
    int img = blockIdx.x;
    const float* L2 = pyr + 6291456 + (size_t)img * 16384;   // lvl2
    // level 3 (64^2) from global lvl2 (128^2)
    for (int t = threadIdx.x; t < 4096; t += 256) {
        int i = t >> 6, j = t & 63;
        float s = 0.0f;
        #pragma unroll
        for (int dy = -1; dy <= 1; ++dy) {
            int y = 2*i + dy;
            #pragma unroll
            for (int dx = -1; dx <= 1; ++dx) {
                int x = 2*j + dx;
                s += (y >= 0 && y < 128 && x >= 0 && x < 128) ? L2[y*128 + x] : OOBV;
            }
        }
        float v = s / 9.0f;
        buf[t] = v;
        pyr[7864320 + (size_t)img * 4096 + t] = v;
    }
    __syncthreads();
    // levels 4..9 from LDS
    int inOff = 0, sin = 64;
    size_t goff = 8257536;
    while (sin > 1) {
        int sout = sin >> 1;
        int outOff = inOff + sin * sin;
        for (int t = threadIdx.x; t < sout * sout; t += 256) {
            int i = t / sout, j = t - i * sout;
            float s = 0.0f;
            for (int dy = -1; dy <= 1; ++dy) {
                int y = 2*i + dy;
                for (int dx = -1; dx <= 1; ++dx) {
                    int x = 2*j + dx;
                    s += (y >= 0 && y < sin && x >= 0 && x < sin) ? buf[inOff + y*sin + x] : OOBV;
                }
            }
            float v = s / 9.0f;
            buf[outOff + t] = v;
            pyr[goff + (size_t)img * sout * sout + t] = v;
        }
        __syncthreads();
        inOff = outOff; sin = sout;
        goff += (size_t)96 * sout * sout;
    }
}

// ---- ga = (grad0 + sum of upsampled levels)/10 ----
// one block per (img, 8-row slab): x-interp constants hoisted to registers
// and reused across the 8 rows; vertical interp rows staged in LDS.
__global__ __launch_bounds__(256) void k_ga(const float* __restrict__ mt,
                                            const float* __restrict__ pyr,
                                            float* __restrict__ ga) {
    __shared__ float vrow[8][520];
    int img = blockIdx.x >> 6;         // 64 slabs per image
    int h0 = (blockIdx.x & 63) * 8;

    // phase 1: vertically interpolated rows of levels 1..9 for 8 output rows
    #pragma unroll
    for (int l = 0; l < 9; ++l) {
        const int s = 256 >> l;
        const int vo = 512 - (512 >> l) + l;
        const float scale = (float)s * (1.0f / 512.0f);
        const float* Lp = pyr + (8388608 - (8388608 >> (2*l))) + (size_t)img * s * s;
        for (int e = threadIdx.x; e < 8*(s+1); e += 256) {
            int r = e / (s+1);                 // constant divisor (unrolled l)
            int x = e - r*(s+1);
            int xx = x < s ? x : s - 1;        // pad slot duplicates last col
            float hf = (float)(h0 + r);
            float fy = (hf + 0.5f) * scale - 0.5f;
            fy = fminf(fmaxf(fy, 0.0f), (float)(s - 1));   // edge clamp
            float fyf = floorf(fy);
            int y0 = (int)fyf;
            float ty = fy - fyf;
            int yb = (y0 + 1 < s) ? y0 + 1 : s - 1;
            float a = Lp[y0*s + xx], b = Lp[yb*s + xx];
            vrow[r][vo + x] = (1.0f - ty) * a + ty * b;
        }
    }
    __syncthreads();

    // per-thread horizontal interp constants for its two columns (regs)
    int   x0v[2][9];
    float txv[2][9];
    #pragma unroll
    for (int rep = 0; rep < 2; ++rep) {
        float wf = (float)(threadIdx.x + rep * 256);
        #pragma unroll
        for (int l = 0; l < 9; ++l) {
            const int s = 256 >> l;
            const float scale = (float)s * (1.0f / 512.0f);
            float fx = (wf + 0.5f) * scale - 0.5f;
            fx = fminf(fmaxf(fx, 0.0f), (float)(s - 1));
            float fxf = floorf(fx);
            x0v[rep][l] = (int)fxf + (512 - (512 >> l) + l);   // vo + x0
            txv[rep][l] = fx - fxf;
        }
    }

    // phase 2: 8 rows x 2 columns per thread
    for (int r = 0; r < 8; ++r) {
        int h = h0 + r;
        #pragma unroll
        for (int rep = 0; rep < 2; ++rep) {
            int w = threadIdx.x + rep * 256;
            int idx = img * HW + h * 512 + w;
            float acc = -mt[idx];              // grad0 (0.01*mo corrected later)
            #pragma unroll
            for (int l = 0; l < 9; ++l) {
                float a = vrow[r][x0v[rep][l]];
                float b = vrow[r][x0v[rep][l] + 1];
                float tx = txv[rep][l];
                acc += (1.0f - tx) * a + tx * b;
            }
            ga[idx] = acc / 10.0f;
        }
    }
}

// ---- ga correction: +0.01/10 at set pixels (dedup'd, so plain RMW is safe) ----
__global__ void k_corrga(const int* __restrict__ cnt, const int* __restrict__ plist,
                         float* __restrict__ ga) {
    int k = blockIdx.x * blockDim.x + threadIdx.x;
    if (k >= *cnt) return;
    ga[plist[k]] += 0.001f;
}

// ---- speculative full trajectory: 10 steps, no grid sync ----
// Gate has latch semantics: trajectories agree with reference up to the first
// t where plmax[t] <= 0.1; k_final truncates if that ever happens.
__global__ __launch_bounds__(256) void k_traj(const float* __restrict__ pts,
                                              const float* __restrict__ mt,
                                              const float* __restrict__ ga,
                                              float* __restrict__ pfin,
                                              float* __restrict__ plmax) {
    int i = blockIdx.x * 256 + threadIdx.x;    // grid exactly 48x256 = NPTS
    float px = pts[2*i], py = pts[2*i+1];
    int img = i >> 7, n = i & 127;
    const float* M = mt + (size_t)img * HW;
    const float* G = ga + (size_t)img * HW;
    float d = expf(-(float)n * 0.078125f);     // exp(-n/128*10)
    float s0 = 0.0f, s1 = 0.0f;

    for (int t = 0; t < 10; ++t) {
        int xi = clampi((int)rintf(px), 0, 511);
        int yi = clampi((int)rintf(py), 0, 511);
        float pl = (1.0f - M[yi*512 + xi]) * d;
        // wave-level max reduce, one atomic per wave per step
        float r = pl;
        #pragma unroll
        for (int off = 32; off; off >>= 1) r = fmaxf(r, __shfl_xor(r, off, 64));
        if ((threadIdx.x & 63) == 0)
            atomicMax((int*)&plmax[t], __float_as_int(r));  // pl>=0 => bit order ok
        float gxp = (G[clampi(yi-1,0,511)*512 + xi] - G[clampi(yi+1,0,511)*512 + xi]) * 0.5f;
        float gyp = (G[yi*512 + clampi(xi-1,0,511)] - G[yi*512 + clampi(xi+1,0,511)]) * 0.5f;
        float g0 = -gyp * pl;                  // x component
        float g1 = -gxp * pl;                  // y component
        s0 = 0.99f * s0 + 0.01f * g0 * g0;
        s1 = 0.99f * s1 + 0.01f * g1 * g1;
        px = px - 0.2f * g0 / (sqrtf(s0) + 1e-8f);
        py = py - 0.2f * g1 / (sqrtf(s1) + 1e-8f);
    }
    pfin[2*i] = px; pfin[2*i+1] = py;
}

// ---- final: truncation fixup (rare) + masks_opt scatter + p_opt write ----
__global__ __launch_bounds__(256) void k_final(const float* __restrict__ pts,
                                               const float* __restrict__ mt,
                                               const float* __restrict__ ga,
                                               const float* __restrict__ pfin,
                                               const float* __restrict__ plmax,
                                               float* __restrict__ mopt,
                                               float* __restrict__ pout) {
    int tstop = 10;
    #pragma unroll
    for (int t = 9; t >= 0; --t)
        if (!(plmax[t] > 0.1f)) tstop = t;
    int i = blockIdx.x * 256 + threadIdx.x;
    float px, py;
    if (tstop == 10) {                         // speculation exact (normal path)
        px = pfin[2*i]; py = pfin[2*i+1];
    } else {                                   // replay truncated trajectory
        px = pts[2*i]; py = pts[2*i+1];
        int img = i >> 7, n = i & 127;
        const float* M = mt + (size_t)img * HW;
        const float* G = ga + (size_t)img * HW;
        float d = expf(-(float)n * 0.078125f);
        float s0 = 0.0f, s1 = 0.0f;
        for (int t = 0; t < tstop; ++t) {
            int xi = clampi((int)rintf(px), 0, 511);
            int yi = clampi((int)rintf(py), 0, 511);
            float pl = (1.0f - M[yi*512 + xi]) * d;
            float gxp = (G[clampi(yi-1,0,511)*512 + xi] - G[clampi(yi+1,0,511)*512 + xi]) * 0.5f;
            float gyp = (G[yi*512 + clampi(xi-1,0,511)] - G[yi*512 + clampi(xi+1,0,511)]) * 0.5f;
            float g0 = -gyp * pl;
            float g1 = -gxp * pl;
            s0 = 0.99f * s0 + 0.01f * g0 * g0;
            s1 = 0.99f * s1 + 0.01f * g1 * g1;
            px = px - 0.2f * g0 / (sqrtf(s0) + 1e-8f);
            py = py - 0.2f * g1 / (sqrtf(s1) + 1e-8f);
        }
    }
    pout[2*i] = px; pout[2*i+1] = py;
    int xi = clampi((int)rintf(px), 0, 511);
    int yi = clampi((int)rintf(py), 0, 511);
    mopt[(i >> 7) * HW + yi*512 + xi] = 1.0f;
}

extern "C" void kernel_launch(void* const* d_in, const int* in_sizes, int n_in,
                              void* d_out, int out_size, void* d_ws, size_t ws_size,
                              hipStream_t stream) {
    const float* pts = (const float*)d_in[0];
    const float* mt  = (const float*)d_in[1];
    if (in_sizes[0] != NPTS * 2) { const float* tmp = pts; pts = mt; mt = tmp; }

    float* out  = (float*)d_out;
    float* mo   = out;                          // masks_out
    float* mopt = out + (size_t)IMGS * HW;      // masks_opt
    float* pout = out + 2 * (size_t)IMGS * HW;  // p_opt

    float* ws    = (float*)d_ws;
    float* pyr   = ws + PYR_OFF;
    float* pfin  = ws + PFIN_OFF;
    float* plmax = ws + PLMAX_OFF;
    int*   cnt   = (int*)(ws + CNT_OFF);
    int*   plist = (int*)(ws + LIST_OFF);
    float* ga    = ws + GA_OFF;

    // zero entire output (masks_out + masks_opt zeros; p_opt overwritten later)
    hipMemsetAsync(out, 0, (size_t)out_size * sizeof(float), stream);
    hipMemsetAsync(plmax, 0, 12 * sizeof(float), stream);   // plmax[0..10] + cnt

    k_scatter<<<NPTS/256, 256, 0, stream>>>(pts, mo, cnt, plist);
    k_lvl1<<<IMGS*65536/256, 256, 0, stream>>>(mt, pyr);
    k_corr1<<<NPTS/256, 256, 0, stream>>>(cnt, plist, pyr);
    k_lvl2<<<IMGS*16384/256, 256, 0, stream>>>(pyr, pyr + 6291456);
    k_pyrtail<<<IMGS, 256, 0, stream>>>(pyr);
    k_ga<<<IMGS*64, 256, 0, stream>>>(mt, pyr, ga);
    k_corrga<<<NPTS/256, 256, 0, stream>>>(cnt, plist, ga);
    k_traj<<<NPTS/256, 256, 0, stream>>>(pts, mt, ga, pfin, plmax);
    k_final<<<NPTS/256, 256, 0, stream>>>(pts, mt, ga, pfin, plmax, mopt, pout);
}